// Round 4
// baseline (587.938 us; speedup 1.0000x reference)
//
#include <hip/hip_runtime.h>
#include <hip/hip_bf16.h>
#include <stdint.h>

#define IN_DIM 256
#define HID_DIM 256
#define OUT_DIM 128

typedef __attribute__((ext_vector_type(8))) short short8;
typedef __attribute__((ext_vector_type(4))) float floatx4;

__device__ __forceinline__ float bf2f(ushort u) {
  union { uint32_t i; float f; } v; v.i = ((uint32_t)u) << 16; return v.f;
}
__device__ __forceinline__ ushort f2bf(float f) {
  union { float f; uint32_t u; } v; v.f = f;
  uint32_t u = v.u;
  uint32_t r = u + 0x7fffu + ((u >> 16) & 1u);  // RNE; finite values only here
  return (ushort)(r >> 16);
}

// ---- fp32 -> bf16 bulk convert (n multiple of 4) ----
__global__ void f2b_kernel(const float* __restrict__ in, ushort* __restrict__ out, int n) {
  int base = (blockIdx.x * 256 + threadIdx.x) * 4;
  if (base < n) {
    float4 v = *(const float4*)(in + base);
    ushort4 o;
    o.x = f2bf(v.x); o.y = f2bf(v.y); o.z = f2bf(v.z); o.w = f2bf(v.w);
    *(ushort4*)(out + base) = o;
  }
}

// ---- degree counting ----
__global__ void deg_kernel(const int* __restrict__ src, const int* __restrict__ dst,
                           int* __restrict__ out_deg, int* __restrict__ in_deg, int E) {
  int e = blockIdx.x * 256 + threadIdx.x;
  if (e < E) {
    atomicAdd(&out_deg[src[e]], 1);
    atomicAdd(&in_deg[dst[e]], 1);
  }
}

__global__ void norm_kernel(const int* __restrict__ out_deg, const int* __restrict__ in_deg,
                            float* __restrict__ out_norm, float* __restrict__ in_norm, int N) {
  int n = blockIdx.x * 256 + threadIdx.x;
  if (n < N) {
    int od = out_deg[n]; if (od < 1) od = 1;
    int id = in_deg[n];  if (id < 1) id = 1;
    out_norm[n] = rsqrtf((float)od);
    in_norm[n]  = rsqrtf((float)id);
  }
}

// ---- 3-stage scan: in_deg -> row_ptr ----
__global__ void scan_sums(const int* __restrict__ deg, int* __restrict__ chunk_sum, int n) {
  __shared__ int lds[256];
  int b = blockIdx.x, t = threadIdx.x;
  int base = b * 1024 + t * 4;
  int s = 0;
  if (base + 3 < n) {
    int4 v = *(const int4*)(deg + base);
    s = v.x + v.y + v.z + v.w;
  } else {
    for (int i = 0; i < 4; ++i) if (base + i < n) s += deg[base + i];
  }
  lds[t] = s;
  __syncthreads();
  for (int off = 128; off > 0; off >>= 1) {
    if (t < off) lds[t] += lds[t + off];
    __syncthreads();
  }
  if (t == 0) chunk_sum[b] = lds[0];
}

__global__ void scan_chunks(const int* __restrict__ chunk_sum, int* __restrict__ chunk_off,
                            int nchunks, int* __restrict__ row_ptr) {
  __shared__ int lds[256];
  int t = threadIdx.x;
  int v = (t < nchunks) ? chunk_sum[t] : 0;
  lds[t] = v;
  __syncthreads();
  for (int off = 1; off < 256; off <<= 1) {
    int add = (t >= off) ? lds[t - off] : 0;
    __syncthreads();
    lds[t] += add;
    __syncthreads();
  }
  if (t < nchunks) chunk_off[t] = lds[t] - v;  // exclusive
  if (t == 0) row_ptr[0] = 0;
}

__global__ void scan_final(const int* __restrict__ deg, const int* __restrict__ chunk_off,
                           int* __restrict__ row_ptr, int n) {
  __shared__ int lds[256];
  int b = blockIdx.x, t = threadIdx.x;
  int base = b * 1024 + t * 4;
  int v[4]; int s = 0;
#pragma unroll
  for (int i = 0; i < 4; ++i) { v[i] = (base + i < n) ? deg[base + i] : 0; s += v[i]; }
  lds[t] = s;
  __syncthreads();
  for (int off = 1; off < 256; off <<= 1) {
    int add = (t >= off) ? lds[t - off] : 0;
    __syncthreads();
    lds[t] += add;
    __syncthreads();
  }
  int run = lds[t] - s + chunk_off[b];
#pragma unroll
  for (int i = 0; i < 4; ++i) {
    run += v[i];
    if (base + i < n) row_ptr[base + i + 1] = run;
  }
}

// ---- bucket edges by dst (CSR fill); also records per-edge weight out_norm[src] ----
__global__ void fill_kernel(const int* __restrict__ src, const int* __restrict__ dst,
                            const int* __restrict__ row_ptr, int* __restrict__ fill_cnt,
                            const float* __restrict__ out_norm,
                            int* __restrict__ edge_src, float* __restrict__ edge_w, int E) {
  int e = blockIdx.x * 256 + threadIdx.x;
  if (e < E) {
    int d = dst[e];
    int s = src[e];
    int pos = row_ptr[d] + atomicAdd(&fill_cnt[d], 1);
    edge_src[pos] = s;
    edge_w[pos] = out_norm[s];
  }
}

// ---- pack transposed bf16 weights + fcW bf16 copy ----
__global__ void prep_weights(const float* __restrict__ W1, const float* __restrict__ W2,
                             const float* __restrict__ W3, const float* __restrict__ b2,
                             const float* __restrict__ b3, const float* __restrict__ fcW,
                             ushort* __restrict__ W1T, ushort* __restrict__ WcT,
                             float* __restrict__ bcat, ushort* __restrict__ fcWb) {
  int k = blockIdx.x;   // 0..255
  int n = threadIdx.x;  // 0..255
  W1T[n * 256 + k] = f2bf(W1[k * 256 + n]);
  WcT[n * 256 + k] = f2bf((n < 128) ? W2[k * 128 + n] : W3[k * 128 + (n - 128)]);
  fcWb[k * 256 + n] = f2bf(fcW[k * 256 + n]);
  if (k == 0) bcat[n] = (n < 128) ? b2[n] : b3[n - 128];
}

// ---- sparse aggregation v2: out[n][:] = in_norm[n] * sum_{e in N_in(n)} edge_w[e]*x[src[e]][:]
// one WAVE per node; half-wave (32 lanes) covers 256 dims with uint4 (8 dims/lane);
// the two halves process different neighbors; 4 neighbors per loop iteration.
__global__ __launch_bounds__(256) void agg_kernel(
    const ushort* __restrict__ x, const int* __restrict__ row_ptr,
    const int* __restrict__ edge_src, const float* __restrict__ edge_w,
    const float* __restrict__ in_norm, ushort* __restrict__ out, int N) {
  int wave = threadIdx.x >> 6, lane = threadIdx.x & 63;
  int n = blockIdx.x * 4 + wave;
  if (n >= N) return;
  int half = lane >> 5;   // 0/1: which neighbor in the pair
  int hl = lane & 31;     // dims 8*hl .. 8*hl+7
  int start = row_ptr[n], end = row_ptr[n + 1];
  float acc[8];
#pragma unroll
  for (int k = 0; k < 8; ++k) acc[k] = 0.f;

  for (int base = start; base < end; base += 4) {
    int i0 = base + half;
    int i1 = base + 2 + half;
    int s0 = 0, s1 = 0; float w0 = 0.f, w1 = 0.f;
    if (i0 < end) { s0 = edge_src[i0]; w0 = edge_w[i0]; }
    if (i1 < end) { s1 = edge_src[i1]; w1 = edge_w[i1]; }
    uint4 v0 = *(const uint4*)&x[(size_t)s0 * 256 + hl * 8];
    uint4 v1 = *(const uint4*)&x[(size_t)s1 * 256 + hl * 8];
    const uint32_t* p0 = (const uint32_t*)&v0;
    const uint32_t* p1 = (const uint32_t*)&v1;
#pragma unroll
    for (int k = 0; k < 4; ++k) {
      acc[2 * k]     += bf2f((ushort)(p0[k] & 0xffffu)) * w0;
      acc[2 * k + 1] += bf2f((ushort)(p0[k] >> 16)) * w0;
      acc[2 * k]     += bf2f((ushort)(p1[k] & 0xffffu)) * w1;
      acc[2 * k + 1] += bf2f((ushort)(p1[k] >> 16)) * w1;
    }
  }
  // combine the two half-wave partials (lane L <-> lane L^32)
#pragma unroll
  for (int k = 0; k < 8; ++k) acc[k] += __shfl_xor(acc[k], 32, 64);

  if (half == 0) {
    float inn = in_norm[n];
    uint4 o;
    uint32_t* po = (uint32_t*)&o;
#pragma unroll
    for (int k = 0; k < 4; ++k) {
      po[k] = ((uint32_t)f2bf(acc[2 * k + 1] * inn) << 16) |
              (uint32_t)f2bf(acc[2 * k] * inn);
    }
    *(uint4*)&out[(size_t)n * 256 + hl * 8] = o;
  }
}

// ---- MFMA GEMM: C = act(A[M x 256] @ BT^T + bias); bf16 inputs, fp32 accum
// block tile 128x128, BK=64 (4 outer K-iters, 8 barriers total)
__global__ __launch_bounds__(256) void gemm_kernel(
    const ushort* __restrict__ A, const ushort* __restrict__ BT,
    const float* __restrict__ bias, float* __restrict__ C32,
    ushort* __restrict__ Cbf, int M, int Nout, int relu) {
  __shared__ alignas(16) ushort A_lds[128 * 72];
  __shared__ alignas(16) ushort B_lds[128 * 72];
  int t = threadIdx.x;
  int m0 = blockIdx.x * 128;
  int n0 = blockIdx.y * 128;
  int wave = t >> 6, lane = t & 63;
  int wm = (wave >> 1) * 64, wn = (wave & 1) * 64;
  int l15 = lane & 15, quad = lane >> 4;

  floatx4 acc[4][4];
#pragma unroll
  for (int i = 0; i < 4; ++i)
#pragma unroll
    for (int j = 0; j < 4; ++j) acc[i][j] = (floatx4)(0.f);

  for (int kc = 0; kc < 256; kc += 64) {
#pragma unroll
    for (int r = 0; r < 4; ++r) {
      int idx = t + r * 256;       // 0..1023
      int row = idx >> 3;          // 0..127
      int c8 = (idx & 7) << 3;     // 0..56
      int grow = m0 + row; if (grow > M - 1) grow = M - 1;
      uint4 va = *(const uint4*)(A + (size_t)grow * 256 + kc + c8);
      *(uint4*)&A_lds[row * 72 + c8] = va;
      uint4 vb = *(const uint4*)(BT + (size_t)(n0 + row) * 256 + kc + c8);
      *(uint4*)&B_lds[row * 72 + c8] = vb;
    }
    __syncthreads();
#pragma unroll
    for (int ko = 0; ko < 2; ++ko) {
      short8 a[4], b[4];
#pragma unroll
      for (int i = 0; i < 4; ++i) {
        a[i] = *(const short8*)&A_lds[(wm + i * 16 + l15) * 72 + ko * 32 + quad * 8];
        b[i] = *(const short8*)&B_lds[(wn + i * 16 + l15) * 72 + ko * 32 + quad * 8];
      }
#pragma unroll
      for (int i = 0; i < 4; ++i)
#pragma unroll
        for (int j = 0; j < 4; ++j)
          acc[i][j] = __builtin_amdgcn_mfma_f32_16x16x32_bf16(a[i], b[j], acc[i][j], 0, 0, 0);
    }
    __syncthreads();
  }

#pragma unroll
  for (int i = 0; i < 4; ++i) {
#pragma unroll
    for (int j = 0; j < 4; ++j) {
      int col = n0 + wn + j * 16 + l15;
      float bv = bias ? bias[col] : 0.f;
#pragma unroll
      for (int r = 0; r < 4; ++r) {
        int row = m0 + wm + i * 16 + quad * 4 + r;
        if (row < M) {
          float v = acc[i][j][r] + bv;
          if (relu) v = fmaxf(v, 0.f);
          size_t o = (size_t)row * Nout + col;
          if (C32) C32[o] = v;
          if (Cbf) Cbf[o] = f2bf(v);
        }
      }
    }
  }
}

// ---- z = relu(mean) + noise * exp(log_std); tmp(bf16) holds [mean | log_std] per row ----
__global__ void z_kernel(const ushort* __restrict__ tmp, const float* __restrict__ noise,
                         float* __restrict__ z, int N) {
  int idx = blockIdx.x * 256 + threadIdx.x;
  if (idx < N * OUT_DIM) {
    int n = idx >> 7, c = idx & 127;
    float m = bf2f(tmp[(size_t)n * 256 + c]);
    float ls = bf2f(tmp[(size_t)n * 256 + 128 + c]);
    float zz = fmaxf(m, 0.f) + noise[idx] * expf(ls);
    z[idx] = zz;
  }
}

extern "C" void kernel_launch(void* const* d_in, const int* in_sizes, int n_in,
                              void* d_out, int out_size, void* d_ws, size_t ws_size,
                              hipStream_t stream) {
  const float* features = (const float*)d_in[0];
  const float* noise    = (const float*)d_in[1];
  const float* W1 = (const float*)d_in[2];
  const float* b1 = (const float*)d_in[3];
  const float* W2 = (const float*)d_in[4];
  const float* b2 = (const float*)d_in[5];
  const float* W3 = (const float*)d_in[6];
  const float* b3 = (const float*)d_in[7];
  const float* fcW = (const float*)d_in[8];
  const int* src = (const int*)d_in[9];
  const int* dst = (const int*)d_in[10];
  const int N = in_sizes[0] / IN_DIM;
  const int E = in_sizes[9];

  float* out = (float*)d_out;
  float* z_out = out;                           // N x 128
  float* h_out = out + (size_t)N * OUT_DIM;     // N x 256
  float* s_out = h_out + (size_t)N * HID_DIM;   // N x 256

  char* w = (char*)d_ws;
  auto carve = [&](size_t bytes) {
    char* p = w;
    w += (bytes + 255) & ~(size_t)255;
    return p;
  };
  ushort* feat_bf = (ushort*)carve((size_t)N * 256 * 2);
  ushort* h_bf    = (ushort*)carve((size_t)N * 256 * 2);
  ushort* agg_buf = (ushort*)carve((size_t)N * 256 * 2);  // aggX then aggH
  ushort* tmp_bf  = (ushort*)carve((size_t)N * 256 * 2);  // [mean | log_std]
  ushort* W1T  = (ushort*)carve(256 * 256 * 2);
  ushort* WcT  = (ushort*)carve(256 * 256 * 2);
  ushort* fcWb = (ushort*)carve(256 * 256 * 2);
  float*  bcat = (float*)carve(256 * 4);
  int* degs    = (int*)carve((size_t)3 * N * 4);          // out_deg | in_deg | fill_cnt
  int* out_deg = degs;
  int* in_deg  = degs + N;
  int* fill_cnt = degs + 2 * N;
  float* out_norm = (float*)carve((size_t)N * 4);
  float* in_norm  = (float*)carve((size_t)N * 4);
  int* row_ptr  = (int*)carve((size_t)(N + 1) * 4);
  int* edge_src = (int*)carve((size_t)E * 4);
  float* edge_w = (float*)carve((size_t)E * 4);
  int* chunk_sum = (int*)carve(256 * 4);
  int* chunk_off = (int*)carve(256 * 4);

  const int nchunks = (N + 1023) / 1024;

  hipMemsetAsync(degs, 0, (size_t)3 * N * 4, stream);
  deg_kernel<<<(E + 255) / 256, 256, 0, stream>>>(src, dst, out_deg, in_deg, E);
  norm_kernel<<<(N + 255) / 256, 256, 0, stream>>>(out_deg, in_deg, out_norm, in_norm, N);
  scan_sums<<<nchunks, 256, 0, stream>>>(in_deg, chunk_sum, N);
  scan_chunks<<<1, 256, 0, stream>>>(chunk_sum, chunk_off, nchunks, row_ptr);
  scan_final<<<nchunks, 256, 0, stream>>>(in_deg, chunk_off, row_ptr, N);
  fill_kernel<<<(E + 255) / 256, 256, 0, stream>>>(src, dst, row_ptr, fill_cnt, out_norm,
                                                   edge_src, edge_w, E);

  f2b_kernel<<<((N * 256 / 4) + 255) / 256, 256, 0, stream>>>(features, feat_bf, N * 256);
  prep_weights<<<256, 256, 0, stream>>>(W1, W2, W3, b2, b3, fcW, W1T, WcT, bcat, fcWb);

  dim3 ggrid((N + 127) / 128, 2);
  // GCN layer 1: aggregate features, then H = relu(agg @ W1 + b1) -> fp32 out + bf16 copy
  agg_kernel<<<(N + 3) / 4, 256, 0, stream>>>(feat_bf, row_ptr, edge_src, edge_w, in_norm, agg_buf, N);
  gemm_kernel<<<ggrid, 256, 0, stream>>>(agg_buf, W1T, b1, h_out, h_bf, N, 256, 1);
  // GCN layer 2: aggregate h, then [mean|log_std] = agg @ [W2|W3] + [b2|b3]
  agg_kernel<<<(N + 3) / 4, 256, 0, stream>>>(h_bf, row_ptr, edge_src, edge_w, in_norm, agg_buf, N);
  gemm_kernel<<<ggrid, 256, 0, stream>>>(agg_buf, WcT, bcat, (float*)nullptr, tmp_bf, N, 256, 0);
  z_kernel<<<(N * OUT_DIM + 255) / 256, 256, 0, stream>>>(tmp_bf, noise, z_out, N);
  // seq_fts = features @ fcW^T
  gemm_kernel<<<ggrid, 256, 0, stream>>>(feat_bf, fcWb, (const float*)nullptr, s_out, (ushort*)nullptr, N, 256, 0);
}

// Round 5
// 547.801 us; speedup vs baseline: 1.0733x; 1.0733x over previous
//
#include <hip/hip_runtime.h>
#include <hip/hip_bf16.h>
#include <stdint.h>
#include <math.h>

#define IN_DIM 256
#define HID_DIM 256
#define OUT_DIM 128

typedef __attribute__((ext_vector_type(8))) short short8;
typedef __attribute__((ext_vector_type(4))) float floatx4;

__device__ __forceinline__ float bf2f(ushort u) {
  union { uint32_t i; float f; } v; v.i = ((uint32_t)u) << 16; return v.f;
}
__device__ __forceinline__ ushort f2bf(float f) {
  union { float f; uint32_t u; } v; v.f = f;
  uint32_t u = v.u;
  uint32_t r = u + 0x7fffu + ((u >> 16) & 1u);  // RNE; finite values only here
  return (ushort)(r >> 16);
}

// ---- fp32 -> bf16 bulk convert (n multiple of 4) ----
__global__ void f2b_kernel(const float* __restrict__ in, ushort* __restrict__ out, int n) {
  int base = (blockIdx.x * 256 + threadIdx.x) * 4;
  if (base < n) {
    float4 v = *(const float4*)(in + base);
    ushort4 o;
    o.x = f2bf(v.x); o.y = f2bf(v.y); o.z = f2bf(v.z); o.w = f2bf(v.w);
    *(ushort4*)(out + base) = o;
  }
}

// ---- degree counting ----
__global__ void deg_kernel(const int* __restrict__ src, const int* __restrict__ dst,
                           int* __restrict__ out_deg, int* __restrict__ in_deg, int E) {
  int e = blockIdx.x * 256 + threadIdx.x;
  if (e < E) {
    atomicAdd(&out_deg[src[e]], 1);
    atomicAdd(&in_deg[dst[e]], 1);
  }
}

// ---- 3-stage scan: in_deg -> row_ptr ----
__global__ void scan_sums(const int* __restrict__ deg, int* __restrict__ chunk_sum, int n) {
  __shared__ int lds[256];
  int b = blockIdx.x, t = threadIdx.x;
  int base = b * 1024 + t * 4;
  int s = 0;
  if (base + 3 < n) {
    int4 v = *(const int4*)(deg + base);
    s = v.x + v.y + v.z + v.w;
  } else {
    for (int i = 0; i < 4; ++i) if (base + i < n) s += deg[base + i];
  }
  lds[t] = s;
  __syncthreads();
  for (int off = 128; off > 0; off >>= 1) {
    if (t < off) lds[t] += lds[t + off];
    __syncthreads();
  }
  if (t == 0) chunk_sum[b] = lds[0];
}

__global__ void scan_chunks(const int* __restrict__ chunk_sum, int* __restrict__ chunk_off,
                            int nchunks, int* __restrict__ row_ptr) {
  __shared__ int lds[256];
  int t = threadIdx.x;
  int v = (t < nchunks) ? chunk_sum[t] : 0;
  lds[t] = v;
  __syncthreads();
  for (int off = 1; off < 256; off <<= 1) {
    int add = (t >= off) ? lds[t - off] : 0;
    __syncthreads();
    lds[t] += add;
    __syncthreads();
  }
  if (t < nchunks) chunk_off[t] = lds[t] - v;  // exclusive
  if (t == 0) row_ptr[0] = 0;
}

__global__ void scan_final(const int* __restrict__ deg, const int* __restrict__ chunk_off,
                           int* __restrict__ row_ptr, int n) {
  __shared__ int lds[256];
  int b = blockIdx.x, t = threadIdx.x;
  int base = b * 1024 + t * 4;
  int v[4]; int s = 0;
#pragma unroll
  for (int i = 0; i < 4; ++i) { v[i] = (base + i < n) ? deg[base + i] : 0; s += v[i]; }
  lds[t] = s;
  __syncthreads();
  for (int off = 1; off < 256; off <<= 1) {
    int add = (t >= off) ? lds[t - off] : 0;
    __syncthreads();
    lds[t] += add;
    __syncthreads();
  }
  int run = lds[t] - s + chunk_off[b];
#pragma unroll
  for (int i = 0; i < 4; ++i) {
    run += v[i];
    if (base + i < n) row_ptr[base + i + 1] = run;
  }
}

// ---- bucket edges by dst (CSR fill); edge weight = rsqrt(out_deg[src]) inline ----
__global__ void fill_kernel(const int* __restrict__ src, const int* __restrict__ dst,
                            const int* __restrict__ row_ptr, int* __restrict__ fill_cnt,
                            const int* __restrict__ out_deg,
                            int* __restrict__ edge_src, float* __restrict__ edge_w, int E) {
  int e = blockIdx.x * 256 + threadIdx.x;
  if (e < E) {
    int d = dst[e];
    int s = src[e];
    int pos = row_ptr[d] + atomicAdd(&fill_cnt[d], 1);
    int od = out_deg[s]; if (od < 1) od = 1;
    edge_src[pos] = s;
    edge_w[pos] = rsqrtf((float)od);
  }
}

// ---- pack transposed bf16 weights + fcW bf16 copy ----
__global__ void prep_weights(const float* __restrict__ W1, const float* __restrict__ W2,
                             const float* __restrict__ W3, const float* __restrict__ b2,
                             const float* __restrict__ b3, const float* __restrict__ fcW,
                             ushort* __restrict__ W1T, ushort* __restrict__ WcT,
                             float* __restrict__ bcat, ushort* __restrict__ fcWb) {
  int k = blockIdx.x;   // 0..255
  int n = threadIdx.x;  // 0..255
  W1T[n * 256 + k] = f2bf(W1[k * 256 + n]);
  WcT[n * 256 + k] = f2bf((n < 128) ? W2[k * 128 + n] : W3[k * 128 + (n - 128)]);
  fcWb[k * 256 + n] = f2bf(fcW[k * 256 + n]);
  if (k == 0) bcat[n] = (n < 128) ? b2[n] : b3[n - 128];
}

// ---- sparse aggregation: out[n][:] = rsqrt(in_deg[n]) * sum_e edge_w[e]*x[src[e]][:]
// one WAVE per node; half-wave covers 256 dims w/ uint4; 4 neighbors/iter
__global__ __launch_bounds__(256) void agg_kernel(
    const ushort* __restrict__ x, const int* __restrict__ row_ptr,
    const int* __restrict__ edge_src, const float* __restrict__ edge_w,
    const int* __restrict__ in_deg, ushort* __restrict__ out, int N) {
  int wave = threadIdx.x >> 6, lane = threadIdx.x & 63;
  int n = blockIdx.x * 4 + wave;
  if (n >= N) return;
  int half = lane >> 5;
  int hl = lane & 31;
  int start = row_ptr[n], end = row_ptr[n + 1];
  float acc[8];
#pragma unroll
  for (int k = 0; k < 8; ++k) acc[k] = 0.f;

  for (int base = start; base < end; base += 4) {
    int i0 = base + half;
    int i1 = base + 2 + half;
    int s0 = 0, s1 = 0; float w0 = 0.f, w1 = 0.f;
    if (i0 < end) { s0 = edge_src[i0]; w0 = edge_w[i0]; }
    if (i1 < end) { s1 = edge_src[i1]; w1 = edge_w[i1]; }
    uint4 v0 = *(const uint4*)&x[(size_t)s0 * 256 + hl * 8];
    uint4 v1 = *(const uint4*)&x[(size_t)s1 * 256 + hl * 8];
    const uint32_t* p0 = (const uint32_t*)&v0;
    const uint32_t* p1 = (const uint32_t*)&v1;
#pragma unroll
    for (int k = 0; k < 4; ++k) {
      acc[2 * k]     += bf2f((ushort)(p0[k] & 0xffffu)) * w0;
      acc[2 * k + 1] += bf2f((ushort)(p0[k] >> 16)) * w0;
      acc[2 * k]     += bf2f((ushort)(p1[k] & 0xffffu)) * w1;
      acc[2 * k + 1] += bf2f((ushort)(p1[k] >> 16)) * w1;
    }
  }
#pragma unroll
  for (int k = 0; k < 8; ++k) acc[k] += __shfl_xor(acc[k], 32, 64);

  if (half == 0) {
    int id = in_deg[n]; if (id < 1) id = 1;
    float inn = rsqrtf((float)id);
    uint4 o;
    uint32_t* po = (uint32_t*)&o;
#pragma unroll
    for (int k = 0; k < 4; ++k) {
      po[k] = ((uint32_t)f2bf(acc[2 * k + 1] * inn) << 16) |
              (uint32_t)f2bf(acc[2 * k] * inn);
    }
    *(uint4*)&out[(size_t)n * 256 + hl * 8] = o;
  }
}

// ---- MFMA GEMM, tile 128x256 (full Nout=256 width), BK=64, 4 waves stacked (32 rows each)
// mode 0: h = relu(A@W + b) -> C32 fp32 + Cbf bf16     (bias = b1)
// mode 1: z = relu(mean) + noise*exp(log_std) -> C32[N x 128]  (bias = bcat[256])
// mode 2: C32 = A@W (no bias)
__global__ __launch_bounds__(256, 2) void gemm_kernel(
    const ushort* __restrict__ A, const ushort* __restrict__ BT,
    const float* __restrict__ bias, const float* __restrict__ noise,
    float* __restrict__ C32, ushort* __restrict__ Cbf, int M, int mode) {
  __shared__ alignas(16) ushort A_lds[128 * 72];
  __shared__ alignas(16) ushort B_lds[256 * 72];
  int t = threadIdx.x;
  int m0 = blockIdx.x * 128;
  int wave = t >> 6, lane = t & 63;
  int wm = wave * 32;
  int l15 = lane & 15, quad = lane >> 4;

  floatx4 acc[2][16];
#pragma unroll
  for (int i = 0; i < 2; ++i)
#pragma unroll
    for (int j = 0; j < 16; ++j) acc[i][j] = (floatx4)(0.f);

  for (int kc = 0; kc < 256; kc += 64) {
#pragma unroll
    for (int r = 0; r < 4; ++r) {           // A: 128 rows x 8 chunks = 1024
      int idx = t + r * 256;
      int row = idx >> 3;
      int c = (idx & 7) << 3;
      int grow = m0 + row; if (grow > M - 1) grow = M - 1;
      *(uint4*)&A_lds[row * 72 + c] = *(const uint4*)(A + (size_t)grow * 256 + kc + c);
    }
#pragma unroll
    for (int r = 0; r < 8; ++r) {           // B: 256 rows x 8 chunks = 2048
      int idx = t + r * 256;
      int row = idx >> 3;
      int c = (idx & 7) << 3;
      *(uint4*)&B_lds[row * 72 + c] = *(const uint4*)(BT + (size_t)row * 256 + kc + c);
    }
    __syncthreads();
#pragma unroll
    for (int ko = 0; ko < 2; ++ko) {
      short8 a[2];
#pragma unroll
      for (int i = 0; i < 2; ++i)
        a[i] = *(const short8*)&A_lds[(wm + i * 16 + l15) * 72 + ko * 32 + quad * 8];
#pragma unroll
      for (int j = 0; j < 16; ++j) {
        short8 b = *(const short8*)&B_lds[(j * 16 + l15) * 72 + ko * 32 + quad * 8];
#pragma unroll
        for (int i = 0; i < 2; ++i)
          acc[i][j] = __builtin_amdgcn_mfma_f32_16x16x32_bf16(a[i], b, acc[i][j], 0, 0, 0);
      }
    }
    __syncthreads();
  }

  if (mode == 1) {
    // z epilogue: cols 0..127 = mean, 128..255 = log_std (same wave)
#pragma unroll
    for (int i = 0; i < 2; ++i) {
#pragma unroll
      for (int j = 0; j < 8; ++j) {
        int col = j * 16 + l15;
        float bm = bias[col];
        float bl = bias[col + 128];
#pragma unroll
        for (int r = 0; r < 4; ++r) {
          int row = m0 + wm + i * 16 + quad * 4 + r;
          if (row < M) {
            float mean = acc[i][j][r] + bm;
            float ls = acc[i][j + 8][r] + bl;
            size_t o = (size_t)row * 128 + col;
            C32[o] = fmaxf(mean, 0.f) + noise[o] * expf(ls);
          }
        }
      }
    }
  } else {
#pragma unroll
    for (int i = 0; i < 2; ++i) {
#pragma unroll
      for (int j = 0; j < 16; ++j) {
        int col = j * 16 + l15;
        float bv = (mode == 0) ? bias[col] : 0.f;
#pragma unroll
        for (int r = 0; r < 4; ++r) {
          int row = m0 + wm + i * 16 + quad * 4 + r;
          if (row < M) {
            float v = acc[i][j][r] + bv;
            if (mode == 0) v = fmaxf(v, 0.f);
            size_t o = (size_t)row * 256 + col;
            C32[o] = v;
            if (mode == 0) Cbf[o] = f2bf(v);
          }
        }
      }
    }
  }
}

extern "C" void kernel_launch(void* const* d_in, const int* in_sizes, int n_in,
                              void* d_out, int out_size, void* d_ws, size_t ws_size,
                              hipStream_t stream) {
  const float* features = (const float*)d_in[0];
  const float* noise    = (const float*)d_in[1];
  const float* W1 = (const float*)d_in[2];
  const float* b1 = (const float*)d_in[3];
  const float* W2 = (const float*)d_in[4];
  const float* b2 = (const float*)d_in[5];
  const float* W3 = (const float*)d_in[6];
  const float* b3 = (const float*)d_in[7];
  const float* fcW = (const float*)d_in[8];
  const int* src = (const int*)d_in[9];
  const int* dst = (const int*)d_in[10];
  const int N = in_sizes[0] / IN_DIM;
  const int E = in_sizes[9];

  float* out = (float*)d_out;
  float* z_out = out;                           // N x 128
  float* h_out = out + (size_t)N * OUT_DIM;     // N x 256
  float* s_out = h_out + (size_t)N * HID_DIM;   // N x 256

  char* w = (char*)d_ws;
  auto carve = [&](size_t bytes) {
    char* p = w;
    w += (bytes + 255) & ~(size_t)255;
    return p;
  };
  ushort* feat_bf = (ushort*)carve((size_t)N * 256 * 2);
  ushort* h_bf    = (ushort*)carve((size_t)N * 256 * 2);
  ushort* agg_buf = (ushort*)carve((size_t)N * 256 * 2);  // aggX then aggH
  ushort* W1T  = (ushort*)carve(256 * 256 * 2);
  ushort* WcT  = (ushort*)carve(256 * 256 * 2);
  ushort* fcWb = (ushort*)carve(256 * 256 * 2);
  float*  bcat = (float*)carve(256 * 4);
  int* degs    = (int*)carve((size_t)3 * N * 4);          // out_deg | in_deg | fill_cnt
  int* out_deg = degs;
  int* in_deg  = degs + N;
  int* fill_cnt = degs + 2 * N;
  int* row_ptr  = (int*)carve((size_t)(N + 1) * 4);
  int* edge_src = (int*)carve((size_t)E * 4);
  float* edge_w = (float*)carve((size_t)E * 4);
  int* chunk_sum = (int*)carve(256 * 4);
  int* chunk_off = (int*)carve(256 * 4);

  const int nchunks = (N + 1023) / 1024;

  hipMemsetAsync(degs, 0, (size_t)3 * N * 4, stream);
  deg_kernel<<<(E + 255) / 256, 256, 0, stream>>>(src, dst, out_deg, in_deg, E);
  scan_sums<<<nchunks, 256, 0, stream>>>(in_deg, chunk_sum, N);
  scan_chunks<<<1, 256, 0, stream>>>(chunk_sum, chunk_off, nchunks, row_ptr);
  scan_final<<<nchunks, 256, 0, stream>>>(in_deg, chunk_off, row_ptr, N);
  fill_kernel<<<(E + 255) / 256, 256, 0, stream>>>(src, dst, row_ptr, fill_cnt, out_deg,
                                                   edge_src, edge_w, E);

  f2b_kernel<<<((N * 256 / 4) + 255) / 256, 256, 0, stream>>>(features, feat_bf, N * 256);
  prep_weights<<<256, 256, 0, stream>>>(W1, W2, W3, b2, b3, fcW, W1T, WcT, bcat, fcWb);

  int gblocks = (N + 127) / 128;
  // GCN layer 1: aggregate features, then H = relu(agg @ W1 + b1) -> fp32 + bf16 copy
  agg_kernel<<<(N + 3) / 4, 256, 0, stream>>>(feat_bf, row_ptr, edge_src, edge_w, in_deg, agg_buf, N);
  gemm_kernel<<<gblocks, 256, 0, stream>>>(agg_buf, W1T, b1, (const float*)nullptr,
                                           h_out, h_bf, N, 0);
  // GCN layer 2 + z fused: [mean|log_std] accumulators -> z directly
  agg_kernel<<<(N + 3) / 4, 256, 0, stream>>>(h_bf, row_ptr, edge_src, edge_w, in_deg, agg_buf, N);
  gemm_kernel<<<gblocks, 256, 0, stream>>>(agg_buf, WcT, bcat, noise,
                                           z_out, (ushort*)nullptr, N, 1);
  // seq_fts = features @ fcW^T
  gemm_kernel<<<gblocks, 256, 0, stream>>>(feat_bf, fcWb, (const float*)nullptr,
                                           (const float*)nullptr, s_out, (ushort*)nullptr, N, 2);
}